// Round 4
// baseline (1470.778 us; speedup 1.0000x reference)
//
#include <hip/hip_runtime.h>
#include <hip/hip_bf16.h>

#define D_MODEL 1024
#define HIDDEN  4096
#define NTOK    16384
#define HP      12288   // [sw1 | w1_0 | w1_1] rows in W1t / cols in W2t
#define HB      8192    // per-token hidden width: shared 4096 + routed 4096
#define GPAD    16640   // 130 * 128 padded grouped-token space

typedef __hip_bfloat16 bf16;
typedef __attribute__((ext_vector_type(8))) short short8;
typedef __attribute__((ext_vector_type(4))) float floatx4;

struct bf16x4 { bf16 a, b, c, d; };

__device__ inline void gload_lds16(const bf16* g, bf16* l) {
    __builtin_amdgcn_global_load_lds(
        (const __attribute__((address_space(1))) void*)g,
        (__attribute__((address_space(3))) void*)l, 16, 0, 0);
}

// ---------------------------------------------------------------------------
// prep: b1_all = [sb1 | b1_0 | b1_1]; addvec[e] init = sb2 + b2_0 + b2_1;
// cnt = 0.  (addvec later gains the unrouted-expert constant via addvec_accum)
// ---------------------------------------------------------------------------
__global__ void prep_small(const float* __restrict__ sb1, const float* __restrict__ b1,
                           const float* __restrict__ sb2, const float* __restrict__ b2,
                           float* __restrict__ b1_all, float* __restrict__ addvec,
                           int* __restrict__ cnt)
{
    int i = blockIdx.x * 256 + threadIdx.x;   // 0..12287
    b1_all[i] = (i < HIDDEN) ? sb1[i] : b1[i - HIDDEN];
    if (i < D_MODEL) {
        float s = sb2[i] + b2[i] + b2[D_MODEL + i];
        addvec[i] = s;
        addvec[D_MODEL + i] = s;
    }
    if (i < 2) cnt[i] = 0;
}

// addvec[1-e][d] += sum_h relu(b1[e][h]) * w2[e][h][d]
__global__ void addvec_accum(const float* __restrict__ b1, const float* __restrict__ w2,
                             float* __restrict__ addvec)
{
    const int blk  = blockIdx.x;
    const int e    = blk >> 6;
    const int hseg = (blk >> 2) & 15;
    const int d    = (blk & 3) * 256 + threadIdx.x;
    const float* B1 = b1 + e * HIDDEN + hseg * 256;
    const float* W  = w2 + (size_t)e * HIDDEN * D_MODEL + (size_t)hseg * 256 * D_MODEL + d;
    float s = 0.f;
    for (int h = 0; h < 256; ++h) {
        float b = B1[h]; b = b > 0.f ? b : 0.f;
        s += b * W[(size_t)h * D_MODEL];
    }
    atomicAdd(&addvec[(1 - e) * D_MODEL + d], s);
}

// 32x32 tiled transpose + fp32->bf16 cast:  dst[c][r] = (bf16)src[r][c]
__global__ void transpose_cast(const float* __restrict__ src, bf16* __restrict__ dst,
                               int R, int Cc, int ldDst)
{
    __shared__ float tile[32][33];
    const int bx = blockIdx.x * 32;
    const int by = blockIdx.y * 32;
    const int tx = threadIdx.x & 31;
    const int ty = threadIdx.x >> 5;
#pragma unroll
    for (int i = 0; i < 32; i += 8)
        tile[ty + i][tx] = src[(size_t)(by + ty + i) * Cc + bx + tx];
    __syncthreads();
#pragma unroll
    for (int i = 0; i < 32; i += 8)
        dst[(size_t)(bx + ty + i) * ldDst + by + tx] = __float2bfloat16(tile[tx][ty + i]);
}

// ---------------------------------------------------------------------------
// Gating: fp32 dot (argmax == softmax-top1), group position via atomics.
// One wave per token.
// ---------------------------------------------------------------------------
__global__ void gate_route(const float* __restrict__ x, const float* __restrict__ gw,
                           int* __restrict__ route, int* __restrict__ pos,
                           int* __restrict__ cnt)
{
    const int token = blockIdx.x * 4 + (threadIdx.x >> 6);
    const int lane  = threadIdx.x & 63;
    const float4* xr = (const float4*)(x + (size_t)token * D_MODEL);
    const float4* g0 = (const float4*)gw;
    const float4* g1 = (const float4*)(gw + D_MODEL);
    float s0 = 0.f, s1 = 0.f;
    for (int i = lane; i < D_MODEL / 4; i += 64) {
        float4 v = xr[i];
        float4 a = g0[i], b = g1[i];
        s0 += v.x * a.x + v.y * a.y + v.z * a.z + v.w * a.w;
        s1 += v.x * b.x + v.y * b.y + v.z * b.z + v.w * b.w;
    }
#pragma unroll
    for (int off = 32; off > 0; off >>= 1) {
        s0 += __shfl_down(s0, off, 64);
        s1 += __shfl_down(s1, off, 64);
    }
    if (lane == 0) {
        int r = (s1 > s0) ? 1 : 0;
        route[token] = r;
        pos[token] = atomicAdd(&cnt[r], 1);
    }
}

// gperm init + per-128-block expert id.  off1 = ceil(count0/128)*128.
__global__ void k_init(const int* __restrict__ cnt, int* __restrict__ gperm,
                       int* __restrict__ blkexp)
{
    int i = blockIdx.x * 256 + threadIdx.x;
    int off1 = ((cnt[0] + 127) >> 7) << 7;
    if (i < GPAD) gperm[i] = -1;
    if (i < GPAD / 128) blkexp[i] = (i * 128 >= off1) ? 1 : 0;
}

__global__ void k_scatter(const int* __restrict__ route, const int* __restrict__ pos,
                          const int* __restrict__ cnt, int* __restrict__ gperm)
{
    int t = blockIdx.x * 256 + threadIdx.x;
    int off1 = ((cnt[0] + 127) >> 7) << 7;
    int g = route[t] ? off1 + pos[t] : pos[t];
    gperm[g] = t;
}

// Xg[g] = bf16(x[gperm[g]]) or 0.  One block per g-row; thread i handles 4 el.
__global__ void gather_cast(const float* __restrict__ x, const int* __restrict__ gperm,
                            bf16* __restrict__ Xg)
{
    const int g = blockIdx.x;
    const int t = gperm[g];
    bf16x4* dst = (bf16x4*)(Xg + (size_t)g * D_MODEL);
    if (t >= 0) {
        const float4* src = (const float4*)(x + (size_t)t * D_MODEL);
        float4 v = src[threadIdx.x];
        bf16x4 o = { __float2bfloat16(v.x), __float2bfloat16(v.y),
                     __float2bfloat16(v.z), __float2bfloat16(v.w) };
        dst[threadIdx.x] = o;
    } else {
        bf16x4 z = { __float2bfloat16(0.f), __float2bfloat16(0.f),
                     __float2bfloat16(0.f), __float2bfloat16(0.f) };
        dst[threadIdx.x] = z;
    }
}

// ---------------------------------------------------------------------------
// Merged grouped GEMM, 128M x 256N tile, 4 waves (each 64M x 128N), BK=32,
// 4x8 grid of mfma_f32_16x16x32_bf16, global_load_lds width-16 staging.
//
// MODE 0 (FFN layer 1): A = Xg chunk [cur,1024], B = W1t [12288,1024].
//   n-cols 0..4095 use shared rows bn; 4096..8191 use rows bn + e*4096.
//   Out: H[row*8192 + col] = bf16 relu(acc + b1_all[col + secOff]).
// MODE 1 (FFN layer 2): A = H chunk [cur,8192], B = W2t [1024,12288].
//   K halves: k<4096 -> B col k (shared); k>=4096 -> col k + e*4096 (expert).
//   Out: scatter out[gperm[row]*1024 + col] = acc + addvec[e*1024 + col].
// ---------------------------------------------------------------------------
template <int MODE>
__global__ __launch_bounds__(256, 2) void gemm_moe(
    const bf16* __restrict__ A, const bf16* __restrict__ B,
    void* __restrict__ Cout, const float* __restrict__ bias,
    const int* __restrict__ blkexp, const int* __restrict__ gperm)
{
    constexpr int  K   = (MODE == 0) ? 1024 : HB;
    constexpr long lda = (MODE == 0) ? 1024 : HB;
    constexpr long ldb = (MODE == 0) ? 1024 : HP;

    __shared__ bf16 lA[128 * 32];   //  8 KB
    __shared__ bf16 lB[256 * 32];   // 16 KB
    const int tid  = threadIdx.x;
    const int lane = tid & 63;
    const int wave = tid >> 6;
    const long bm = (long)blockIdx.y * 128;
    const long bn = (long)blockIdx.x * 256;
    const int  e  = blkexp[blockIdx.y];

    // B row base: MODE 0 remaps expert n-section; MODE 1 rows are out-dims.
    const long bnB   = (MODE == 0) ? (bn + ((bn >= HIDDEN) ? (long)e * HIDDEN : 0)) : bn;
    const long secOff = (MODE == 0) ? ((bn >= HIDDEN) ? (long)e * HIDDEN : 0) : 0;

    const int sr = lane >> 2;          // row within 16-row staging chunk
    const int sc = (lane & 3) * 8;     // 8 bf16 = 16 B per lane

    const bf16* Ag[2]; const bf16* Bg[4];
    bf16* lAd[2]; bf16* lBd[4];
#pragma unroll
    for (int q = 0; q < 2; q++) {
        const int ch = wave + 4 * q;               // 0..7
        Ag[q]  = A + (bm + ch * 16 + sr) * lda + sc;
        lAd[q] = &lA[ch * 512];
    }
#pragma unroll
    for (int q = 0; q < 4; q++) {
        const int ch = wave + 4 * q;               // 0..15
        Bg[q]  = B + (bnB + ch * 16 + sr) * ldb + sc;
        lBd[q] = &lB[ch * 512];
    }

    const int wr = (wave >> 1) * 64;   // wave row quadrant (0/64)
    const int wc = (wave & 1) * 128;   // wave col half (0/128)
    const int fr = lane & 15;
    const int fk = (lane >> 4) * 8;

    floatx4 acc[4][8];
#pragma unroll
    for (int i = 0; i < 4; i++)
#pragma unroll
        for (int j = 0; j < 8; j++) acc[i][j] = (floatx4){0.f, 0.f, 0.f, 0.f};

    for (int kt = 0; kt < K; kt += 32) {
        if (MODE == 1 && kt == HIDDEN && e != 0) {   // jump to expert-1 cols
#pragma unroll
            for (int q = 0; q < 4; q++) Bg[q] += (long)HIDDEN;
        }
#pragma unroll
        for (int q = 0; q < 2; q++) { gload_lds16(Ag[q], lAd[q]); Ag[q] += 32; }
#pragma unroll
        for (int q = 0; q < 4; q++) { gload_lds16(Bg[q], lBd[q]); Bg[q] += 32; }
        __syncthreads();
        short8 af[4], bfr[8];
#pragma unroll
        for (int i = 0; i < 4; i++)
            af[i] = *(const short8*)&lA[(wr + i * 16 + fr) * 32 + fk];
#pragma unroll
        for (int j = 0; j < 8; j++)
            bfr[j] = *(const short8*)&lB[(wc + j * 16 + fr) * 32 + fk];
#pragma unroll
        for (int i = 0; i < 4; i++)
#pragma unroll
            for (int j = 0; j < 8; j++)
                acc[i][j] = __builtin_amdgcn_mfma_f32_16x16x32_bf16(af[i], bfr[j], acc[i][j], 0, 0, 0);
        __syncthreads();
    }

    // epilogue: C/D layout col = lane&15, row = (lane>>4)*4 + reg
    const int rq = (lane >> 4) * 4;
    int trow[16];
    if (MODE == 1) {
#pragma unroll
        for (int i = 0; i < 4; i++)
#pragma unroll
            for (int r = 0; r < 4; r++)
                trow[i * 4 + r] = gperm[bm + wr + i * 16 + rq + r];
    }
#pragma unroll
    for (int j = 0; j < 8; j++) {
        const long col = bn + wc + j * 16 + fr;
        const float bv = (MODE == 0) ? bias[col + secOff] : bias[(long)e * D_MODEL + col];
#pragma unroll
        for (int i = 0; i < 4; i++) {
#pragma unroll
            for (int r = 0; r < 4; r++) {
                const long row = bm + wr + i * 16 + rq + r;
                float v = acc[i][j][r] + bv;
                if (MODE == 0) {
                    v = v > 0.f ? v : 0.f;
                    ((bf16*)Cout)[row * (long)HB + col] = __float2bfloat16(v);
                } else {
                    int t = trow[i * 4 + r];
                    if (t >= 0)
                        ((float*)Cout)[(size_t)t * D_MODEL + col] = v;
                }
            }
        }
    }
}

// ---------------------------------------------------------------------------
extern "C" void kernel_launch(void* const* d_in, const int* in_sizes, int n_in,
                              void* d_out, int out_size, void* d_ws, size_t ws_size,
                              hipStream_t stream)
{
    const float* x   = (const float*)d_in[0];
    const float* gw  = (const float*)d_in[1];
    const float* w1  = (const float*)d_in[2];   // [2, 1024, 4096]
    const float* b1  = (const float*)d_in[3];   // [2, 4096]
    const float* w2  = (const float*)d_in[4];   // [2, 4096, 1024]
    const float* b2  = (const float*)d_in[5];   // [2, 1024]
    const float* sw1 = (const float*)d_in[6];   // [1024, 4096]
    const float* sb1 = (const float*)d_in[7];
    const float* sw2 = (const float*)d_in[8];   // [4096, 1024]
    const float* sb2 = (const float*)d_in[9];
    float* out = (float*)d_out;

    // ---- workspace carve-up (fixed ~85 MB + H chunk) ---------------------
    char* p = (char*)d_ws;
    bf16* Xg      = (bf16*)p;  p += (size_t)GPAD * D_MODEL * 2;    // 34 MB
    bf16* W1t     = (bf16*)p;  p += (size_t)HP * D_MODEL * 2;      // 25 MB [12288,1024]
    bf16* W2t     = (bf16*)p;  p += (size_t)D_MODEL * HP * 2;      // 25 MB [1024,12288]
    int*  route   = (int*)p;   p += (size_t)NTOK * 4;
    int*  pos     = (int*)p;   p += (size_t)NTOK * 4;
    int*  gperm   = (int*)p;   p += (size_t)GPAD * 4;
    int*  blkexp  = (int*)p;   p += (size_t)(GPAD / 128) * 4;
    int*  cnt     = (int*)p;   p += 2 * 4;
    float* b1_all = (float*)p; p += (size_t)HP * 4;
    float* addvec = (float*)p; p += (size_t)2 * D_MODEL * 4;
    bf16* H       = (bf16*)p;                                      // rest

    const size_t used_fixed = (size_t)(p - (char*)d_ws);
    const size_t avail = (ws_size > used_fixed) ? (ws_size - used_fixed) : 0;
    long cs = (long)(avail / ((size_t)HB * 2));   // tokens per H chunk
    cs = (cs / 128) * 128;
    if (cs > GPAD) cs = GPAD;
    if (cs < 128) cs = 128;

    prep_small<<<HP / 256, 256, 0, stream>>>(sb1, b1, sb2, b2, b1_all, addvec, cnt);
    addvec_accum<<<128, 256, 0, stream>>>(b1, w2, addvec);

    // W1t rows h: [0,4096)=shared, [4096,8192)=e0, [8192,12288)=e1 ; ld 1024
    transpose_cast<<<dim3(HIDDEN / 32, D_MODEL / 32), 256, 0, stream>>>(
        sw1, W1t, D_MODEL, HIDDEN, D_MODEL);
    transpose_cast<<<dim3(HIDDEN / 32, D_MODEL / 32), 256, 0, stream>>>(
        w1, W1t + (size_t)HIDDEN * D_MODEL, D_MODEL, HIDDEN, D_MODEL);
    transpose_cast<<<dim3(HIDDEN / 32, D_MODEL / 32), 256, 0, stream>>>(
        w1 + (size_t)D_MODEL * HIDDEN, W1t + (size_t)2 * HIDDEN * D_MODEL, D_MODEL, HIDDEN, D_MODEL);
    // W2t [1024 rows, ld 12288]: cols [0,4096)=shared, then e0, e1
    transpose_cast<<<dim3(D_MODEL / 32, HIDDEN / 32), 256, 0, stream>>>(
        sw2, W2t, HIDDEN, D_MODEL, HP);
    transpose_cast<<<dim3(D_MODEL / 32, HIDDEN / 32), 256, 0, stream>>>(
        w2, W2t + HIDDEN, HIDDEN, D_MODEL, HP);
    transpose_cast<<<dim3(D_MODEL / 32, HIDDEN / 32), 256, 0, stream>>>(
        w2 + (size_t)HIDDEN * D_MODEL, W2t + (size_t)2 * HIDDEN, HIDDEN, D_MODEL, HP);

    gate_route<<<NTOK / 4, 256, 0, stream>>>(x, gw, route, pos, cnt);
    k_init<<<(GPAD + 255) / 256, 256, 0, stream>>>(cnt, gperm, blkexp);
    k_scatter<<<NTOK / 256, 256, 0, stream>>>(route, pos, cnt, gperm);
    gather_cast<<<GPAD, 256, 0, stream>>>(x, gperm, Xg);

    for (long g0 = 0; g0 < GPAD; g0 += cs) {
        const long cur = (GPAD - g0 < cs) ? (GPAD - g0) : cs;
        gemm_moe<0><<<dim3(HB / 256, cur / 128), 256, 0, stream>>>(
            Xg + g0 * D_MODEL, W1t, H, b1_all, blkexp + g0 / 128, nullptr);
        gemm_moe<1><<<dim3(D_MODEL / 256, cur / 128), 256, 0, stream>>>(
            H, W2t, (void*)out, addvec, blkexp + g0 / 128, gperm + g0);
    }
}